// Round 2
// baseline (222.770 us; speedup 1.0000x reference)
//
#include <hip/hip_runtime.h>

// Problem constants (from reference setup_inputs)
#define BB  16
#define LL  100
#define LOC 2000
#define EE  16

// SU=500, SL=0, TU=3600, TL=0
// out[b,l,j,e] = base[e] + coef[e] * ds[j]
//   base[e] = esl[m,e] + etl[m,e]*(1-wt) + etu[m,e]*wt,  wt = vec[b,l]/3600
//   coef[e] = (esu[m,e]-esl[m,e]) / 500
//   ds[j]   = valid ? mat2[row, j] : 0
//
// Key structural decision: the store loop's data comes from LDS (lgkmcnt),
// NOT from global loads (vmcnt). Loads and stores share vmcnt on CDNA, so a
// store loop with register-preloaded global data forces each "wait for my
// load" to also drain all previously-issued stores (in-order counter) —
// collapsing store in-flight depth to ~1 and throttling the write stream to
// ~2 TB/s. With LDS sourcing, the store stream contains zero vmcnt waits and
// drains like a memset (~6.6 TB/s proven by the harness fill).
__global__ __launch_bounds__(256) void embed_kernel(
    const int*   __restrict__ traj_loc,   // (B,L)
    const float* __restrict__ mat2,       // (LOC,LOC)
    const float* __restrict__ vec,        // (B,L)
    const int*   __restrict__ traj_len,   // (B,)
    const float* __restrict__ emb_sl,     // (2,E)
    const float* __restrict__ emb_su,     // (2,E)
    const float* __restrict__ emb_tl,     // (2,E)
    const float* __restrict__ emb_tu,     // (2,E)
    float*       __restrict__ out)        // (B,L,LOC,E)
{
    __shared__ float srow[LOC];           // 8000 B — 6.25 blocks/CU * 8KB = 50KB/CU, no occupancy hit

    const int bl = blockIdx.x;            // 0 .. B*L-1
    const int b  = bl / LL;
    const int l  = bl - b * LL;

    const bool valid = l < traj_len[b];   // block-uniform
    const int  m     = valid ? 1 : 0;

    int row = traj_loc[bl] - 1;
    row = min(max(row, 0), LOC - 1);

    const float dt = vec[bl];
    const float wt = dt * (1.0f / 3600.0f);   // dt/(TU-TL)

    const int tid = threadIdx.x;
    const int e0  = (tid & 3) * 4;            // this thread's 4 consecutive e's
    const int j0  = tid >> 2;                 // 0..63 (j lane); wave writes 1KB contiguous

    // Per-(b,l) constants: out[j,e] = base[e] + coef[e] * ds[j]
    float base[4], coef[4];
    #pragma unroll
    for (int k = 0; k < 4; ++k) {
        const int e  = e0 + k;
        const float sl = emb_sl[m * EE + e];
        const float su = emb_su[m * EE + e];
        const float tl = emb_tl[m * EE + e];
        const float tu = emb_tu[m * EE + e];
        base[k] = sl + tl * (1.0f - wt) + tu * wt;
        coef[k] = (su - sl) * (1.0f / 500.0f); // /(SU-SL)
    }

    float* __restrict__ outp = out + (size_t)bl * LOC * EE;

    if (valid) {
        // ---- Stage mat2 row into LDS: 500 float4 loads, fully coalesced.
        // row*LOC*4 = row*8000 bytes -> 16B-aligned. ----
        const float4* __restrict__ rp4 =
            reinterpret_cast<const float4*>(mat2 + (size_t)row * LOC);
        float4* __restrict__ s4 = reinterpret_cast<float4*>(srow);
        s4[tid] = rp4[tid];                               // tid 0..255 < 500
        if (tid < (LOC / 4 - 256)) s4[tid + 256] = rp4[tid + 256];  // 244 more
        __syncthreads();

        // ---- Store stream: data from LDS (lgkmcnt waits only). No vmem
        // loads here => compiler emits NO vmcnt waits => stores free-flow.
        // LDS read pattern: 16 distinct banks, 4-lane broadcast — conflict-free.
        #pragma unroll
        for (int i = 0; i < 31; ++i) {                    // j = j0+64i <= 1983
            const int j = j0 + 64 * i;
            const float ds = srow[j];
            float4 v;
            v.x = fmaf(coef[0], ds, base[0]);
            v.y = fmaf(coef[1], ds, base[1]);
            v.z = fmaf(coef[2], ds, base[2]);
            v.w = fmaf(coef[3], ds, base[3]);
            *reinterpret_cast<float4*>(outp + (size_t)j * EE + e0) = v;
        }
        if (j0 < 16) {                                    // tail: j = j0+1984 <= 1999
            const int j = j0 + 64 * 31;
            const float ds = srow[j];
            float4 v;
            v.x = fmaf(coef[0], ds, base[0]);
            v.y = fmaf(coef[1], ds, base[1]);
            v.z = fmaf(coef[2], ds, base[2]);
            v.w = fmaf(coef[3], ds, base[3]);
            *reinterpret_cast<float4*>(outp + (size_t)j * EE + e0) = v;
        }
    } else {
        // ds == 0 everywhere: constant per-thread value, pure store stream.
        float4 v;
        v.x = base[0];
        v.y = base[1];
        v.z = base[2];
        v.w = base[3];
        #pragma unroll
        for (int i = 0; i < 31; ++i) {
            const int j = j0 + 64 * i;
            *reinterpret_cast<float4*>(outp + (size_t)j * EE + e0) = v;
        }
        if (j0 < 16) {
            const int j = j0 + 64 * 31;
            *reinterpret_cast<float4*>(outp + (size_t)j * EE + e0) = v;
        }
    }
}

extern "C" void kernel_launch(void* const* d_in, const int* in_sizes, int n_in,
                              void* d_out, int out_size, void* d_ws, size_t ws_size,
                              hipStream_t stream) {
    const int*   traj_loc = (const int*)  d_in[0];
    const float* mat2     = (const float*)d_in[1];
    const float* vec      = (const float*)d_in[2];
    const int*   traj_len = (const int*)  d_in[3];
    const float* emb_sl   = (const float*)d_in[4];
    const float* emb_su   = (const float*)d_in[5];
    const float* emb_tl   = (const float*)d_in[6];
    const float* emb_tu   = (const float*)d_in[7];
    float* out = (float*)d_out;

    embed_kernel<<<BB * LL, 256, 0, stream>>>(
        traj_loc, mat2, vec, traj_len, emb_sl, emb_su, emb_tl, emb_tu, out);
}